// Round 1
// baseline (256.840 us; speedup 1.0000x reference)
//
#include <hip/hip_runtime.h>
#include <math.h>

#define LC 8
#define FAC 120
#define KS 5
#define KK 25
#define IH 64
#define IWID 64
#define NH 60
#define SS 3600
#define NPIX 57600      // 8*2*3600
#define NBLK2 900       // NPIX/64
#define FPW 30          // perms per wave (120/4)

// ws layout (floats)
#define WS_M 0          // [960][25] : M[(l*120+f)*25 + a*5+d]
#define WS_MSQL 24000   // [8]       : ||K_l||^2

__global__ void k1_build(const float* __restrict__ kern, float* __restrict__ ws,
                         float* __restrict__ out_tail) {
  const int t = threadIdx.x;
  // copy kernel input to output tail (second tuple element)
  for (int i = t; i < LC * KK; i += 1024) out_tail[i] = kern[i];
  if (t < LC * FAC) {
    const int l = t / FAC;
    const int f = t - l * FAC;
    // lexicographic permutation decode (matches itertools.permutations)
    int avail[KS] = {0, 1, 2, 3, 4};
    int perm[KS];
    int rem = f;
    const int divs[4] = {24, 6, 2, 1};
    for (int i = 0; i < 4; ++i) {
      const int d = rem / divs[i];
      rem -= d * divs[i];
      perm[i] = avail[d];
      for (int j = d; j < 4 - i; ++j) avail[j] = avail[j + 1];
    }
    perm[4] = avail[0];
    const float* Kl = kern + l * KK;
    float* Mrow = ws + WS_M + t * KK;
    #pragma unroll
    for (int a = 0; a < KS; ++a)
      #pragma unroll
      for (int d = 0; d < KS; ++d)
        Mrow[a * KS + d] = Kl[perm[a] * KS + perm[d]];
    if (f == 0) {
      float s = 0.f;
      #pragma unroll
      for (int q = 0; q < KK; ++q) s = fmaf(Kl[q], Kl[q], s);
      ws[WS_MSQL + l] = s;
    }
  }
}

__global__ __launch_bounds__(256) void k2_feat(const float* __restrict__ x,
                                               const float* __restrict__ ws,
                                               float* __restrict__ outfeat) {
  __shared__ float sm[4][LC][64];
  __shared__ float xsqs[64];
  const int tid = threadIdx.x;
  const int w = tid >> 6;
  const int lane = tid & 63;
  const int u = blockIdx.x * 64 + lane;   // pixel index: (b*2+cp)*3600 + s
  const int plane = u / SS;
  const int s = u - plane * SS;
  const int ih = s / NH;
  const int iw = s - ih * NH;
  const float* xb = x + plane * (IH * IWID) + ih * IWID + iw;
  float p[KK];
  #pragma unroll
  for (int a = 0; a < KS; ++a)
    #pragma unroll
    for (int d = 0; d < KS; ++d)
      p[a * KS + d] = xb[a * IWID + d];
  if (w == 0) {
    float xs = 0.f;
    #pragma unroll
    for (int q = 0; q < KK; ++q) xs = fmaf(p[q], p[q], xs);
    xsqs[lane] = xs;
  }
  // force wave-uniform f-group so M addresses become scalar loads
  const int wu = __builtin_amdgcn_readfirstlane(w);
  const float* __restrict__ M = ws + WS_M;
  float maxd[LC];
  #pragma unroll
  for (int l = 0; l < LC; ++l) maxd[l] = -INFINITY;
  const int f0 = wu * FPW;
  for (int j = 0; j < FPW; ++j) {
    const int f = f0 + j;
    float acc[LC];
    #pragma unroll
    for (int l = 0; l < LC; ++l) acc[l] = 0.f;
    #pragma unroll
    for (int q = 0; q < KK; ++q) {
      #pragma unroll
      for (int l = 0; l < LC; ++l)
        acc[l] = fmaf(p[q], M[(l * FAC + f) * KK + q], acc[l]);  // SGPR operand
    }
    #pragma unroll
    for (int l = 0; l < LC; ++l) maxd[l] = fmaxf(maxd[l], acc[l]);
  }
  #pragma unroll
  for (int l = 0; l < LC; ++l) sm[w][l][lane] = maxd[l];
  __syncthreads();
  // combine the 4 waves' maxima, add norms, write feature in (b,c,s) layout
  #pragma unroll
  for (int it = 0; it < 2; ++it) {
    const int idx = tid + it * 256;
    const int l = idx >> 6;
    const int ln = idx & 63;
    const float m4 = fmaxf(fmaxf(sm[0][l][ln], sm[1][l][ln]),
                           fmaxf(sm[2][l][ln], sm[3][l][ln]));
    const int uu = blockIdx.x * 64 + ln;
    const int pl = uu / SS;
    const int ssx = uu - pl * SS;
    const int b = pl >> 1;
    const int cp = pl & 1;
    const float fv = ws[WS_MSQL + l] + xsqs[ln] - 2.f * m4;
    outfeat[((b * 16) + (cp * 8) + l) * SS + ssx] = fv;
  }
}

__global__ __launch_bounds__(512) void k3_softmax(float* __restrict__ data) {
  const int row = blockIdx.x;   // b*16 + c
  float* __restrict__ dr = data + row * SS;
  const int tid = threadIdx.x;
  float v[8];
  float mn = INFINITY;
  #pragma unroll
  for (int i = 0; i < 8; ++i) {
    const int s = tid + i * 512;
    const float f = (s < SS) ? dr[s] : INFINITY;
    v[i] = f;
    mn = fminf(mn, f);
  }
  __shared__ float red[8];
  #pragma unroll
  for (int off = 32; off >= 1; off >>= 1) mn = fminf(mn, __shfl_xor(mn, off));
  if ((tid & 63) == 0) red[tid >> 6] = mn;
  __syncthreads();
  float tmn = red[0];
  #pragma unroll
  for (int i = 1; i < 8; ++i) tmn = fminf(tmn, red[i]);
  __syncthreads();
  float sum = 0.f;
  #pragma unroll
  for (int i = 0; i < 8; ++i) {
    const float e = expf(tmn - v[i]);   // exp(min - f) <= 1; OOB lanes give exp(-inf)=0
    v[i] = e;
    sum += e;
  }
  #pragma unroll
  for (int off = 32; off >= 1; off >>= 1) sum += __shfl_xor(sum, off);
  if ((tid & 63) == 0) red[tid >> 6] = sum;
  __syncthreads();
  float tot = red[0];
  #pragma unroll
  for (int i = 1; i < 8; ++i) tot += red[i];
  const float inv = 1.0f / tot;
  #pragma unroll
  for (int i = 0; i < 8; ++i) {
    const int s = tid + i * 512;
    if (s < SS) dr[s] = v[i] * inv;
  }
}

extern "C" void kernel_launch(void* const* d_in, const int* in_sizes, int n_in,
                              void* d_out, int out_size, void* d_ws, size_t ws_size,
                              hipStream_t stream) {
  const float* x = (const float*)d_in[0];
  const float* kern = (const float*)d_in[1];
  float* out = (float*)d_out;
  float* ws = (float*)d_ws;
  hipLaunchKernelGGL(k1_build, dim3(1), dim3(1024), 0, stream, kern, ws, out + 460800);
  hipLaunchKernelGGL(k2_feat, dim3(NBLK2), dim3(256), 0, stream, x, ws, out);
  hipLaunchKernelGGL(k3_softmax, dim3(128), dim3(512), 0, stream, out);
}

// Round 2
// 256.045 us; speedup vs baseline: 1.0031x; 1.0031x over previous
//
#include <hip/hip_runtime.h>
#include <math.h>

#define LC 8
#define FAC 120
#define KS 5
#define KK 25
#define IH 64
#define IWID 64
#define NH 60
#define SS 3600
#define NPIX 57600      // 8*2*3600
#define NBLK2 900       // NPIX/64
#define FPW 30          // perms per wave (120/4)

// ws layout (floats)
#define WS_M 0          // [960][25] : M[(l*120+f)*25 + a*5+d]
#define WS_MSQL 24000   // [8]       : ||K_l||^2

__global__ void k1_build(const float* __restrict__ kern, float* __restrict__ ws,
                         float* __restrict__ out_tail) {
  const int t = threadIdx.x;
  // copy kernel input to output tail (second tuple element)
  for (int i = t; i < LC * KK; i += 1024) out_tail[i] = kern[i];
  if (t < LC * FAC) {
    const int l = t / FAC;
    const int f = t - l * FAC;
    // lexicographic permutation decode (matches itertools.permutations)
    int avail[KS] = {0, 1, 2, 3, 4};
    int perm[KS];
    int rem = f;
    const int divs[4] = {24, 6, 2, 1};
    for (int i = 0; i < 4; ++i) {
      const int d = rem / divs[i];
      rem -= d * divs[i];
      perm[i] = avail[d];
      for (int j = d; j < 4 - i; ++j) avail[j] = avail[j + 1];
    }
    perm[4] = avail[0];
    const float* Kl = kern + l * KK;
    float* Mrow = ws + WS_M + t * KK;
    #pragma unroll
    for (int a = 0; a < KS; ++a)
      #pragma unroll
      for (int d = 0; d < KS; ++d)
        Mrow[a * KS + d] = Kl[perm[a] * KS + perm[d]];
    if (f == 0) {
      float s = 0.f;
      #pragma unroll
      for (int q = 0; q < KK; ++q) s = fmaf(Kl[q], Kl[q], s);
      ws[WS_MSQL + l] = s;
    }
  }
}

__global__ __launch_bounds__(256, 2) void k2_feat(const float* __restrict__ x,
                                                  const float* __restrict__ ws,
                                                  float* __restrict__ outfeat) {
  __shared__ float sm[4][LC][64];
  __shared__ float xsqs[64];
  const int tid = threadIdx.x;
  const int w = tid >> 6;
  const int lane = tid & 63;
  const int u = blockIdx.x * 64 + lane;   // pixel index: (b*2+cp)*3600 + s
  const int plane = u / SS;
  const int s = u - plane * SS;
  const int ih = s / NH;
  const int iw = s - ih * NH;
  const float* xb = x + plane * (IH * IWID) + ih * IWID + iw;
  float p[KK];
  #pragma unroll
  for (int a = 0; a < KS; ++a)
    #pragma unroll
    for (int d = 0; d < KS; ++d)
      p[a * KS + d] = xb[a * IWID + d];
  // Pin the patch in VGPRs: forbids the scheduler from rematerializing the
  // global loads inside the j-loop (round-1 failure mode: VGPR=24, VALU 15%).
  #pragma unroll
  for (int q = 0; q < KK; ++q) asm volatile("" : "+v"(p[q]));
  if (w == 0) {
    float xs = 0.f;
    #pragma unroll
    for (int q = 0; q < KK; ++q) xs = fmaf(p[q], p[q], xs);
    xsqs[lane] = xs;
  }
  // force wave-uniform f-group so M addresses become scalar loads
  const int wu = __builtin_amdgcn_readfirstlane(w);
  const float* __restrict__ M = ws + WS_M;
  float maxd[LC];
  #pragma unroll
  for (int l = 0; l < LC; ++l) maxd[l] = -INFINITY;
  const int f0 = wu * FPW;
  for (int j = 0; j < FPW; ++j) {
    const int f = f0 + j;
    float acc[LC];
    #pragma unroll
    for (int l = 0; l < LC; ++l) acc[l] = 0.f;
    #pragma unroll
    for (int q = 0; q < KK; ++q) {
      #pragma unroll
      for (int l = 0; l < LC; ++l)
        acc[l] = fmaf(p[q], M[(l * FAC + f) * KK + q], acc[l]);  // SGPR operand
    }
    #pragma unroll
    for (int l = 0; l < LC; ++l) maxd[l] = fmaxf(maxd[l], acc[l]);
  }
  #pragma unroll
  for (int l = 0; l < LC; ++l) sm[w][l][lane] = maxd[l];
  __syncthreads();
  // combine the 4 waves' maxima, add norms, write feature in (b,c,s) layout
  #pragma unroll
  for (int it = 0; it < 2; ++it) {
    const int idx = tid + it * 256;
    const int l = idx >> 6;
    const int ln = idx & 63;
    const float m4 = fmaxf(fmaxf(sm[0][l][ln], sm[1][l][ln]),
                           fmaxf(sm[2][l][ln], sm[3][l][ln]));
    const int uu = blockIdx.x * 64 + ln;
    const int pl = uu / SS;
    const int ssx = uu - pl * SS;
    const int b = pl >> 1;
    const int cp = pl & 1;
    const float fv = ws[WS_MSQL + l] + xsqs[ln] - 2.f * m4;
    outfeat[((b * 16) + (cp * 8) + l) * SS + ssx] = fv;
  }
}

__global__ __launch_bounds__(512) void k3_softmax(float* __restrict__ data) {
  const int row = blockIdx.x;   // b*16 + c
  float* __restrict__ dr = data + row * SS;
  const int tid = threadIdx.x;
  float v[8];
  float mn = INFINITY;
  #pragma unroll
  for (int i = 0; i < 8; ++i) {
    const int s = tid + i * 512;
    const float f = (s < SS) ? dr[s] : INFINITY;
    v[i] = f;
    mn = fminf(mn, f);
  }
  __shared__ float red[8];
  #pragma unroll
  for (int off = 32; off >= 1; off >>= 1) mn = fminf(mn, __shfl_xor(mn, off));
  if ((tid & 63) == 0) red[tid >> 6] = mn;
  __syncthreads();
  float tmn = red[0];
  #pragma unroll
  for (int i = 1; i < 8; ++i) tmn = fminf(tmn, red[i]);
  __syncthreads();
  float sum = 0.f;
  #pragma unroll
  for (int i = 0; i < 8; ++i) {
    const float e = expf(tmn - v[i]);   // exp(min - f) <= 1; OOB lanes give exp(-inf)=0
    v[i] = e;
    sum += e;
  }
  #pragma unroll
  for (int off = 32; off >= 1; off >>= 1) sum += __shfl_xor(sum, off);
  if ((tid & 63) == 0) red[tid >> 6] = sum;
  __syncthreads();
  float tot = red[0];
  #pragma unroll
  for (int i = 1; i < 8; ++i) tot += red[i];
  const float inv = 1.0f / tot;
  #pragma unroll
  for (int i = 0; i < 8; ++i) {
    const int s = tid + i * 512;
    if (s < SS) dr[s] = v[i] * inv;
  }
}

extern "C" void kernel_launch(void* const* d_in, const int* in_sizes, int n_in,
                              void* d_out, int out_size, void* d_ws, size_t ws_size,
                              hipStream_t stream) {
  const float* x = (const float*)d_in[0];
  const float* kern = (const float*)d_in[1];
  float* out = (float*)d_out;
  float* ws = (float*)d_ws;
  hipLaunchKernelGGL(k1_build, dim3(1), dim3(1024), 0, stream, kern, ws, out + 460800);
  hipLaunchKernelGGL(k2_feat, dim3(NBLK2), dim3(256), 0, stream, x, ws, out);
  hipLaunchKernelGGL(k3_softmax, dim3(128), dim3(512), 0, stream, out);
}

// Round 3
// 38.586 us; speedup vs baseline: 6.6563x; 6.6357x over previous
//
#include <hip/hip_runtime.h>
#include <math.h>

#define LC 8
#define FAC 120
#define KS 5
#define KK 25
#define IWID 64
#define NH 60
#define SS 3600
#define NBLK2 900       // 57600/64
#define FPW 30          // perms per wave (120/4)

// Compile-time lexicographic permutation table (matches itertools.permutations).
struct PermTable { int p[FAC][KS]; };
constexpr PermTable make_perms() {
  PermTable t{};
  for (int f = 0; f < FAC; ++f) {
    int avail[KS] = {0, 1, 2, 3, 4};
    int rem = f;
    const int divs[4] = {24, 6, 2, 1};
    for (int i = 0; i < 4; ++i) {
      const int d = rem / divs[i];
      rem -= d * divs[i];
      t.p[f][i] = avail[d];
      for (int j = d; j < KS - 1 - i; ++j) avail[j] = avail[j + 1];
    }
    t.p[f][KS - 1] = avail[0];
  }
  return t;
}
constexpr PermTable PT = make_perms();

// k1: ||K_l||^2 into ws[0..7]; copy kernel to output tail.
__global__ void k1_build(const float* __restrict__ kern, float* __restrict__ ws,
                         float* __restrict__ out_tail) {
  const int t = threadIdx.x;
  for (int i = t; i < LC * KK; i += 256) out_tail[i] = kern[i];
  if (t < LC) {
    const float* Kl = kern + t * KK;
    float s = 0.f;
    #pragma unroll
    for (int q = 0; q < KK; ++q) s = fmaf(Kl[q], Kl[q], s);
    ws[t] = s;
  }
}

// Per-wave compute for f in [F0, F0+30): permutation applied as compile-time
// register renaming on the K index — no M table, no per-f memory traffic.
template<int F0>
__device__ __forceinline__ void wave_compute(const float p[KK],
                                             const float* __restrict__ kern,
                                             float (* __restrict__ smw)[64],
                                             const int lane) {
  #pragma unroll 1   // keep code size down: 8 passes over a 780-instr body
  for (int l = 0; l < LC; ++l) {
    const float* kc = kern + l * KK;
    float ks[KK];
    #pragma unroll
    for (int q = 0; q < KK; ++q) ks[q] = kc[q];   // wave-uniform -> scalar loads
    float md = -INFINITY;
    #pragma unroll
    for (int jj = 0; jj < FPW; ++jj) {
      float acc = 0.f;
      #pragma unroll
      for (int a = 0; a < KS; ++a) {
        const int pa = PT.p[F0 + jj][a] * KS;     // folds to a constant
        #pragma unroll
        for (int d = 0; d < KS; ++d)
          acc = fmaf(p[a * KS + d], ks[pa + PT.p[F0 + jj][d]], acc);
      }
      md = fmaxf(md, acc);
    }
    smw[l][lane] = md;   // runtime-l store goes to LDS, not scratch
  }
}

__global__ __launch_bounds__(256) void k2_feat(const float* __restrict__ x,
                                               const float* __restrict__ kern,
                                               const float* __restrict__ ws,
                                               float* __restrict__ outfeat) {
  __shared__ float sm[4][LC][64];
  __shared__ float xsqs[64];
  const int tid = threadIdx.x;
  const int w = tid >> 6;
  const int lane = tid & 63;
  const int u = blockIdx.x * 64 + lane;   // pixel index: (b*2+cp)*3600 + s
  const int plane = u / SS;
  const int s = u - plane * SS;
  const int ih = s / NH;
  const int iw = s - ih * NH;
  const float* xb = x + plane * (IWID * IWID) + ih * IWID + iw;
  float p[KK];
  #pragma unroll
  for (int a = 0; a < KS; ++a)
    #pragma unroll
    for (int d = 0; d < KS; ++d)
      p[a * KS + d] = xb[a * IWID + d];
  // Pin the patch in VGPRs (insurance against rematerialization).
  #pragma unroll
  for (int q = 0; q < KK; ++q) asm volatile("" : "+v"(p[q]));
  if (w == 0) {
    float xs = 0.f;
    #pragma unroll
    for (int q = 0; q < KK; ++q) xs = fmaf(p[q], p[q], xs);
    xsqs[lane] = xs;
  }
  // wave-uniform f-group selection -> scalar branch, 4 specialized code paths
  const int wu = __builtin_amdgcn_readfirstlane(w);
  if (wu == 0)      wave_compute<0>  (p, kern, sm[0], lane);
  else if (wu == 1) wave_compute<30> (p, kern, sm[1], lane);
  else if (wu == 2) wave_compute<60> (p, kern, sm[2], lane);
  else              wave_compute<90> (p, kern, sm[3], lane);
  __syncthreads();
  // combine the 4 waves' maxima, add norms, write feature in (b,c,s) layout
  #pragma unroll
  for (int it = 0; it < 2; ++it) {
    const int idx = tid + it * 256;
    const int l = idx >> 6;
    const int ln = idx & 63;
    const float m4 = fmaxf(fmaxf(sm[0][l][ln], sm[1][l][ln]),
                           fmaxf(sm[2][l][ln], sm[3][l][ln]));
    const int uu = blockIdx.x * 64 + ln;
    const int pl = uu / SS;
    const int ssx = uu - pl * SS;
    const int b = pl >> 1;
    const int cp = pl & 1;
    const float fv = ws[l] + xsqs[ln] - 2.f * m4;
    outfeat[((b * 16) + (cp * 8) + l) * SS + ssx] = fv;
  }
}

__global__ __launch_bounds__(512) void k3_softmax(float* __restrict__ data) {
  const int row = blockIdx.x;   // b*16 + c
  float* __restrict__ dr = data + row * SS;
  const int tid = threadIdx.x;
  float v[8];
  float mn = INFINITY;
  #pragma unroll
  for (int i = 0; i < 8; ++i) {
    const int s = tid + i * 512;
    const float f = (s < SS) ? dr[s] : INFINITY;
    v[i] = f;
    mn = fminf(mn, f);
  }
  __shared__ float red[8];
  #pragma unroll
  for (int off = 32; off >= 1; off >>= 1) mn = fminf(mn, __shfl_xor(mn, off));
  if ((tid & 63) == 0) red[tid >> 6] = mn;
  __syncthreads();
  float tmn = red[0];
  #pragma unroll
  for (int i = 1; i < 8; ++i) tmn = fminf(tmn, red[i]);
  __syncthreads();
  float sum = 0.f;
  #pragma unroll
  for (int i = 0; i < 8; ++i) {
    const float e = expf(tmn - v[i]);   // exp(min - f) <= 1; OOB lanes give exp(-inf)=0
    v[i] = e;
    sum += e;
  }
  #pragma unroll
  for (int off = 32; off >= 1; off >>= 1) sum += __shfl_xor(sum, off);
  if ((tid & 63) == 0) red[tid >> 6] = sum;
  __syncthreads();
  float tot = red[0];
  #pragma unroll
  for (int i = 1; i < 8; ++i) tot += red[i];
  const float inv = 1.0f / tot;
  #pragma unroll
  for (int i = 0; i < 8; ++i) {
    const int s = tid + i * 512;
    if (s < SS) dr[s] = v[i] * inv;
  }
}

extern "C" void kernel_launch(void* const* d_in, const int* in_sizes, int n_in,
                              void* d_out, int out_size, void* d_ws, size_t ws_size,
                              hipStream_t stream) {
  const float* x = (const float*)d_in[0];
  const float* kern = (const float*)d_in[1];
  float* out = (float*)d_out;
  float* ws = (float*)d_ws;
  hipLaunchKernelGGL(k1_build, dim3(1), dim3(256), 0, stream, kern, ws, out + 460800);
  hipLaunchKernelGGL(k2_feat, dim3(NBLK2), dim3(256), 0, stream, x, kern, ws, out);
  hipLaunchKernelGGL(k3_softmax, dim3(128), dim3(512), 0, stream, out);
}

// Round 4
// 35.988 us; speedup vs baseline: 7.1367x; 1.0722x over previous
//
#include <hip/hip_runtime.h>
#include <math.h>

#define LC 8
#define FAC 120
#define KS 5
#define KK 25
#define IWID 64
#define NH 60
#define SS 3600
#define NPIX 57600       // 8*2*3600
#define PIXB 256         // pixels per block (k2)
#define NBLK2 225        // 57600/256

using bf16x8 = __attribute__((ext_vector_type(8))) short;
using f32x4  = __attribute__((ext_vector_type(4))) float;

// ws layout (bytes):
//   [0      , 65536)  : M_hi  [8][128][32] bf16 (pad f-rows 120..127 and q 25..31 = 0)
//   [65536  , 131072) : M_lo  same shape
//   [131072 , 131104) : msq[8] f32
#define MS_LO_OFF 32768   // in shorts
#define MSQ_BYTE  131072

__device__ __forceinline__ short f2bf(float v) {
  unsigned u = __builtin_bit_cast(unsigned, v);
  unsigned r = u + 0x7FFFu + ((u >> 16) & 1u);   // round-to-nearest-even
  return (short)(r >> 16);
}
__device__ __forceinline__ float bf2f(short h) {
  unsigned u = ((unsigned)(unsigned short)h) << 16;
  return __builtin_bit_cast(float, u);
}

// k1: build split M tables + msq, copy kernel to output tail.
__global__ __launch_bounds__(1024) void k1_build(const float* __restrict__ kern,
                                                 void* __restrict__ wsv,
                                                 float* __restrict__ out_tail) {
  const int t = threadIdx.x;
  for (int i = t; i < LC * KK; i += 1024) out_tail[i] = kern[i];
  short* MH = (short*)wsv;
  short* ML = MH + MS_LO_OFF;
  float* MSQ = (float*)((char*)wsv + MSQ_BYTE);
  const int l = t >> 7;          // t = l*128 + f, t < 1024
  const int f = t & 127;
  short* h = MH + t * 32;
  short* lo = ML + t * 32;
  if (f < FAC) {
    int avail[KS] = {0, 1, 2, 3, 4};
    int perm[KS];
    int rem = f;
    const int divs[4] = {24, 6, 2, 1};
    for (int i = 0; i < 4; ++i) {
      const int d = rem / divs[i];
      rem -= d * divs[i];
      perm[i] = avail[d];
      for (int j = d; j < 4 - i; ++j) avail[j] = avail[j + 1];
    }
    perm[4] = avail[0];
    const float* Kl = kern + l * KK;
    #pragma unroll
    for (int a = 0; a < KS; ++a)
      #pragma unroll
      for (int d = 0; d < KS; ++d) {
        const float v = Kl[perm[a] * KS + perm[d]];
        const short hs = f2bf(v);
        h[a * KS + d] = hs;
        lo[a * KS + d] = f2bf(v - bf2f(hs));
      }
    #pragma unroll
    for (int q = KK; q < 32; ++q) { h[q] = 0; lo[q] = 0; }
    if (f == 0) {
      float s = 0.f;
      #pragma unroll
      for (int q = 0; q < KK; ++q) s = fmaf(Kl[q], Kl[q], s);
      MSQ[l] = s;
    }
  } else {
    #pragma unroll
    for (int q = 0; q < 32; ++q) { h[q] = 0; lo[q] = 0; }
  }
}

// k2: MFMA cross-term + in-register max reduce + feature write.
__global__ __launch_bounds__(256) void k2_feat(const float* __restrict__ x,
                                               const void* __restrict__ wsv,
                                               float* __restrict__ outfeat) {
  __shared__ short pat_hi[PIXB][32];
  __shared__ short pat_lo[PIXB][32];
  __shared__ float xsq_s[PIXB];
  const short* MH = (const short*)wsv;
  const float* MSQ = (const float*)((const char*)wsv + MSQ_BYTE);

  const int tid = threadIdx.x;
  const int w = tid >> 6;
  const int lane = tid & 63;
  const int u0 = blockIdx.x * PIXB;

  // ---- patch gather + fp32 xsq + hi/lo split into LDS ----
  {
    const int u = u0 + tid;
    const int plane = u / SS;
    const int s = u - plane * SS;
    const int ih = s / NH;
    const int iw = s - ih * NH;
    const float* xb = x + plane * (IWID * IWID) + ih * IWID + iw;
    float p[KK];
    #pragma unroll
    for (int a = 0; a < KS; ++a)
      #pragma unroll
      for (int d = 0; d < KS; ++d)
        p[a * KS + d] = xb[a * IWID + d];
    float xs = 0.f;
    #pragma unroll
    for (int q = 0; q < KK; ++q) xs = fmaf(p[q], p[q], xs);
    xsq_s[tid] = xs;
    #pragma unroll
    for (int q = 0; q < KK; ++q) {
      const short hs = f2bf(p[q]);
      pat_hi[tid][q] = hs;
      pat_lo[tid][q] = f2bf(p[q] - bf2f(hs));
    }
    #pragma unroll
    for (int q = KK; q < 32; ++q) { pat_hi[tid][q] = 0; pat_lo[tid][q] = 0; }
  }
  __syncthreads();

  float xs4[4];
  #pragma unroll
  for (int j = 0; j < 4; ++j) xs4[j] = xsq_s[(w << 6) + (j << 4) + (lane & 15)];

  // A-fragment base (per lane): row = l*128 + t*16 + (lane&15), k-chunk (lane>>4)*8
  const short* abase = MH + ((lane & 15) * 32) + ((lane >> 4) * 8);

  auto LOADA = [&](bf16x8* Ah, bf16x8* Al, int l) {
    const short* bh = abase + l * (128 * 32);
    #pragma unroll
    for (int t = 0; t < 8; ++t) {
      Ah[t] = *(const bf16x8*)(bh + t * 512);
      Al[t] = *(const bf16x8*)(bh + t * 512 + MS_LO_OFF);
    }
  };

  auto JL = [&](const bf16x8* Ah, const bf16x8* Al, int l) {
    const float ml = MSQ[l];
    #pragma unroll
    for (int j = 0; j < 4; ++j) {
      const int prow = (w << 6) + (j << 4) + (lane & 15);
      const bf16x8 BH = *(const bf16x8*)&pat_hi[prow][(lane >> 4) * 8];
      const bf16x8 BL = *(const bf16x8*)&pat_lo[prow][(lane >> 4) * 8];
      f32x4 C[8];
      #pragma unroll
      for (int t = 0; t < 8; ++t) {
        C[t] = f32x4{0.f, 0.f, 0.f, 0.f};
        C[t] = __builtin_amdgcn_mfma_f32_16x16x32_bf16(Ah[t], BH, C[t], 0, 0, 0);
        C[t] = __builtin_amdgcn_mfma_f32_16x16x32_bf16(Al[t], BH, C[t], 0, 0, 0);
        C[t] = __builtin_amdgcn_mfma_f32_16x16x32_bf16(Ah[t], BL, C[t], 0, 0, 0);
      }
      float mx = -INFINITY;
      #pragma unroll
      for (int t = 0; t < 7; ++t)
        #pragma unroll
        for (int r = 0; r < 4; ++r) mx = fmaxf(mx, C[t][r]);
      if (lane < 32) {   // tile 7: f-rows 112+(lane>>4)*4+r valid only for f<120
        #pragma unroll
        for (int r = 0; r < 4; ++r) mx = fmaxf(mx, C[7][r]);
      }
      mx = fmaxf(mx, __shfl_xor(mx, 16));
      mx = fmaxf(mx, __shfl_xor(mx, 32));
      const float fv = ml + xs4[j] - 2.f * mx;
      if (lane < 16) {
        const int up = u0 + (w << 6) + (j << 4) + lane;
        const int pl = up / SS;
        const int sx = up - pl * SS;
        outfeat[(((pl >> 1) * 16) + ((pl & 1) * 8) + l) * SS + sx] = fv;
      }
    }
  };

  // software pipeline over l (named double buffers; all indices compile-time)
  bf16x8 A0h[8], A0l[8], A1h[8], A1l[8];
  LOADA(A0h, A0l, 0);
  #pragma unroll 1
  for (int lp = 0; lp < 4; ++lp) {
    const int l0 = lp * 2;
    LOADA(A1h, A1l, l0 + 1);
    JL(A0h, A0l, l0);
    if (lp < 3) LOADA(A0h, A0l, l0 + 2);
    JL(A1h, A1l, l0 + 1);
  }
}

__global__ __launch_bounds__(512) void k3_softmax(float* __restrict__ data) {
  const int row = blockIdx.x;   // b*16 + c
  float* __restrict__ dr = data + row * SS;
  const int tid = threadIdx.x;
  float v[8];
  float mn = INFINITY;
  #pragma unroll
  for (int i = 0; i < 8; ++i) {
    const int s = tid + i * 512;
    const float f = (s < SS) ? dr[s] : INFINITY;
    v[i] = f;
    mn = fminf(mn, f);
  }
  __shared__ float red[8];
  #pragma unroll
  for (int off = 32; off >= 1; off >>= 1) mn = fminf(mn, __shfl_xor(mn, off));
  if ((tid & 63) == 0) red[tid >> 6] = mn;
  __syncthreads();
  float tmn = red[0];
  #pragma unroll
  for (int i = 1; i < 8; ++i) tmn = fminf(tmn, red[i]);
  __syncthreads();
  float sum = 0.f;
  #pragma unroll
  for (int i = 0; i < 8; ++i) {
    const float e = expf(tmn - v[i]);
    v[i] = e;
    sum += e;
  }
  #pragma unroll
  for (int off = 32; off >= 1; off >>= 1) sum += __shfl_xor(sum, off);
  if ((tid & 63) == 0) red[tid >> 6] = sum;
  __syncthreads();
  float tot = red[0];
  #pragma unroll
  for (int i = 1; i < 8; ++i) tot += red[i];
  const float inv = 1.0f / tot;
  #pragma unroll
  for (int i = 0; i < 8; ++i) {
    const int s = tid + i * 512;
    if (s < SS) dr[s] = v[i] * inv;
  }
}

extern "C" void kernel_launch(void* const* d_in, const int* in_sizes, int n_in,
                              void* d_out, int out_size, void* d_ws, size_t ws_size,
                              hipStream_t stream) {
  const float* x = (const float*)d_in[0];
  const float* kern = (const float*)d_in[1];
  float* out = (float*)d_out;
  hipLaunchKernelGGL(k1_build, dim3(1), dim3(1024), 0, stream, kern, d_ws, out + 460800);
  hipLaunchKernelGGL(k2_feat, dim3(NBLK2), dim3(256), 0, stream, x, d_ws, out);
  hipLaunchKernelGGL(k3_softmax, dim3(128), dim3(512), 0, stream, out);
}